// Round 1
// baseline (260.110 us; speedup 1.0000x reference)
//
#include <hip/hip_runtime.h>

#define SEQ  4096
#define DMODEL 1024

typedef __bf16 bf16x8 __attribute__((ext_vector_type(8)));
typedef unsigned short u16x8 __attribute__((ext_vector_type(8)));
typedef float f32x4 __attribute__((ext_vector_type(4)));

// ---------- helpers ----------
static __device__ __forceinline__ unsigned short f2bfbits(float f) {
    unsigned int u = __builtin_bit_cast(unsigned int, f);
    unsigned int lsb = (u >> 16) & 1u;
    u += 0x7fffu + lsb;                      // round-to-nearest-even
    return (unsigned short)(u >> 16);
}

static __device__ __forceinline__ bf16x8 ld_frag(const unsigned short* p) {
    uint4 u = *reinterpret_cast<const uint4*>(p);
    return __builtin_bit_cast(bf16x8, u);
}

// ---------- kernel 1: weights -> bf16 W^T [192][1024] ----------
__global__ void prep_weights(const float* __restrict__ Wq,
                             const float* __restrict__ Wk,
                             const float* __restrict__ Wv,
                             unsigned short* __restrict__ Wt) {
    int i = blockIdx.x * 256 + threadIdx.x;      // 192*1024 total
    int n = i >> 10, k = i & 1023;
    float v;
    if (n < 64)       v = Wq[k * 64 + n];
    else if (n < 128) v = Wk[k * 64 + (n - 64)];
    else              v = Wv[k * 64 + (n - 128)];
    Wt[n * 1024 + k] = f2bfbits(v);
}

// ---------- kernel 2: QKV projection (MFMA bf16) ----------
// grid 256 blocks x 256 thr; block = 64 tokens; wave = 16 tokens x 192 outs
__global__ __launch_bounds__(256) void proj_qkv(
        const float* __restrict__ emb, const unsigned short* __restrict__ Wt,
        const float* __restrict__ bq, const float* __restrict__ bk,
        const float* __restrict__ bv,
        unsigned short* __restrict__ Qb, unsigned short* __restrict__ Kb,
        unsigned short* __restrict__ VT) {
    __shared__ __align__(16) unsigned short Wl[192 * 40];  // [n][32k] pad->40
    const int tid = threadIdx.x;
    const int w = tid >> 6, lane = tid & 63;
    const int c = lane & 15, qd = lane >> 4;
    const int mbase = blockIdx.x * 64 + w * 16;

    f32x4 acc[12];
#pragma unroll
    for (int i = 0; i < 12; i++) acc[i] = (f32x4){0.f, 0.f, 0.f, 0.f};

    for (int k0 = 0; k0 < DMODEL; k0 += 32) {
        __syncthreads();
#pragma unroll
        for (int i = 0; i < 3; i++) {            // 768 16B-chunks of [192][32]
            int ch = tid + 256 * i;
            int n = ch >> 2, koff = (ch & 3) * 8;
            uint4 d = *reinterpret_cast<const uint4*>(Wt + n * 1024 + k0 + koff);
            *reinterpret_cast<uint4*>(&Wl[n * 40 + koff]) = d;
        }
        __syncthreads();

        const float* ap = emb + (size_t)(mbase + c) * DMODEL + k0 + qd * 8;
        float4 a0 = *reinterpret_cast<const float4*>(ap);
        float4 a1 = *reinterpret_cast<const float4*>(ap + 4);
        u16x8 at;
        at[0] = f2bfbits(a0.x); at[1] = f2bfbits(a0.y);
        at[2] = f2bfbits(a0.z); at[3] = f2bfbits(a0.w);
        at[4] = f2bfbits(a1.x); at[5] = f2bfbits(a1.y);
        at[6] = f2bfbits(a1.z); at[7] = f2bfbits(a1.w);
        bf16x8 af = __builtin_bit_cast(bf16x8, at);

#pragma unroll
        for (int nt = 0; nt < 12; nt++) {
            bf16x8 bfr = ld_frag(&Wl[(nt * 16 + c) * 40 + qd * 8]);
            acc[nt] = __builtin_amdgcn_mfma_f32_16x16x32_bf16(af, bfr, acc[nt], 0, 0, 0);
        }
    }

#pragma unroll
    for (int nt = 0; nt < 12; nt++) {
        int n = nt * 16 + c;
        float bias = (n < 64) ? bq[n] : (n < 128) ? bk[n - 64] : bv[n - 128];
#pragma unroll
        for (int r = 0; r < 4; r++) {
            int token = mbase + qd * 4 + r;
            unsigned short bits = f2bfbits(acc[nt][r] + bias);
            if (n < 64)        Qb[(size_t)token * 64 + n] = bits;
            else if (n < 128)  Kb[(size_t)token * 64 + (n - 64)] = bits;
            else {
                int bb = token >> 12, s = token & 4095;
                VT[((size_t)bb * 64 + (n - 128)) * SEQ + s] = bits;
            }
        }
    }
}

// ---------- kernel 3: flash attention ----------
// grid 256 blocks (4 batches x 64 q-blocks); 4 waves x 16 q-rows; t-tile 64
__global__ __launch_bounds__(256) void attn(
        const unsigned short* __restrict__ Qb, const unsigned short* __restrict__ Kb,
        const unsigned short* __restrict__ VT, float* __restrict__ out) {
    __shared__ __align__(16) unsigned short Kt[64 * 72];    // [t][64k] pad->72
    __shared__ __align__(16) unsigned short Vt[64 * 72];    // [v][64t] pad->72
    __shared__ __align__(16) unsigned short Pl[4][16 * 72]; // per-wave P [q][64t]

    const int tid = threadIdx.x;
    const int w = tid >> 6, lane = tid & 63;
    const int c = lane & 15, qd = lane >> 4;
    const int b = blockIdx.x >> 6;
    const int qbase = (blockIdx.x & 63) * 64 + w * 16;
    const float kLS = 0.18033688011112042f;  // log2(e)/8

    const unsigned short* Qp = Qb + ((size_t)(b << 12) + qbase + c) * 64 + qd * 8;
    bf16x8 aq0 = ld_frag(Qp);
    bf16x8 aq1 = ld_frag(Qp + 32);

    f32x4 acc[4];
#pragma unroll
    for (int i = 0; i < 4; i++) acc[i] = (f32x4){0.f, 0.f, 0.f, 0.f};
    float m_r[4] = {-3.0e38f, -3.0e38f, -3.0e38f, -3.0e38f};
    float l_r[4] = {0.f, 0.f, 0.f, 0.f};

    for (int t0 = 0; t0 < SEQ; t0 += 64) {
        __syncthreads();
#pragma unroll
        for (int i = 0; i < 2; i++) {            // 512 chunks each for K and V
            int ch = tid + 256 * i;
            int tr = ch >> 3, koff = (ch & 7) * 8;
            *reinterpret_cast<uint4*>(&Kt[tr * 72 + koff]) =
                *reinterpret_cast<const uint4*>(Kb + ((size_t)(b << 12) + t0 + tr) * 64 + koff);
            *reinterpret_cast<uint4*>(&Vt[tr * 72 + koff]) =
                *reinterpret_cast<const uint4*>(VT + ((size_t)b * 64 + tr) * SEQ + t0 + koff);
        }
        __syncthreads();

        // scores: 4 tiles of 16 t
        f32x4 s[4];
#pragma unroll
        for (int ts = 0; ts < 4; ts++) {
            bf16x8 bk0 = ld_frag(&Kt[(ts * 16 + c) * 72 + qd * 8]);
            bf16x8 bk1 = ld_frag(&Kt[(ts * 16 + c) * 72 + 32 + qd * 8]);
            f32x4 z = (f32x4){0.f, 0.f, 0.f, 0.f};
            z = __builtin_amdgcn_mfma_f32_16x16x32_bf16(aq0, bk0, z, 0, 0, 0);
            z = __builtin_amdgcn_mfma_f32_16x16x32_bf16(aq1, bk1, z, 0, 0, 0);
            s[ts] = z;
        }

        // online softmax (rows = qd*4+r, cols spread over 16 lanes of the quad)
        float mx[4];
#pragma unroll
        for (int r = 0; r < 4; r++)
            mx[r] = fmaxf(fmaxf(s[0][r], s[1][r]), fmaxf(s[2][r], s[3][r]));
#pragma unroll
        for (int off = 1; off < 16; off <<= 1)
#pragma unroll
            for (int r = 0; r < 4; r++)
                mx[r] = fmaxf(mx[r], __shfl_xor(mx[r], off));

        float alpha[4];
#pragma unroll
        for (int r = 0; r < 4; r++) {
            float mn = fmaxf(m_r[r], mx[r]);
            alpha[r] = exp2f((m_r[r] - mn) * kLS);
            m_r[r] = mn;
        }
        float pv[4][4];
#pragma unroll
        for (int ts = 0; ts < 4; ts++)
#pragma unroll
            for (int r = 0; r < 4; r++)
                pv[ts][r] = exp2f((s[ts][r] - m_r[r]) * kLS);
#pragma unroll
        for (int r = 0; r < 4; r++) {
            float sm = pv[0][r] + pv[1][r] + pv[2][r] + pv[3][r];
#pragma unroll
            for (int off = 1; off < 16; off <<= 1) sm += __shfl_xor(sm, off);
            l_r[r] = l_r[r] * alpha[r] + sm;
        }
#pragma unroll
        for (int nt = 0; nt < 4; nt++)
#pragma unroll
            for (int r = 0; r < 4; r++) acc[nt][r] *= alpha[r];

        // P -> LDS (C-layout to A-layout transform)
#pragma unroll
        for (int ts = 0; ts < 4; ts++)
#pragma unroll
            for (int r = 0; r < 4; r++)
                Pl[w][(qd * 4 + r) * 72 + ts * 16 + c] = f2bfbits(pv[ts][r]);

        bf16x8 ap0 = ld_frag(&Pl[w][c * 72 + qd * 8]);
        bf16x8 ap1 = ld_frag(&Pl[w][c * 72 + 32 + qd * 8]);
#pragma unroll
        for (int nt = 0; nt < 4; nt++) {
            bf16x8 bv0 = ld_frag(&Vt[(nt * 16 + c) * 72 + qd * 8]);
            bf16x8 bv1 = ld_frag(&Vt[(nt * 16 + c) * 72 + 32 + qd * 8]);
            acc[nt] = __builtin_amdgcn_mfma_f32_16x16x32_bf16(ap0, bv0, acc[nt], 0, 0, 0);
            acc[nt] = __builtin_amdgcn_mfma_f32_16x16x32_bf16(ap1, bv1, acc[nt], 0, 0, 0);
        }
    }

#pragma unroll
    for (int nt = 0; nt < 4; nt++) {
#pragma unroll
        for (int r = 0; r < 4; r++) {
            int q = qbase + qd * 4 + r;
            out[(((size_t)b << 12) + q) * 64 + nt * 16 + c] = acc[nt][r] / l_r[r];
        }
    }
}

// ---------- launch ----------
extern "C" void kernel_launch(void* const* d_in, const int* in_sizes, int n_in,
                              void* d_out, int out_size, void* d_ws, size_t ws_size,
                              hipStream_t stream) {
    const float* emb = (const float*)d_in[0];
    const float* Wq  = (const float*)d_in[1];
    const float* bq  = (const float*)d_in[2];
    const float* Wk  = (const float*)d_in[3];
    const float* bk  = (const float*)d_in[4];
    const float* Wv  = (const float*)d_in[5];
    const float* bv  = (const float*)d_in[6];
    float* out = (float*)d_out;

    unsigned short* ws = (unsigned short*)d_ws;
    unsigned short* Wt = ws;                       // 192*1024
    unsigned short* Qb = ws + 192 * 1024;          // 4*4096*64
    unsigned short* Kb = Qb + 4 * 4096 * 64;       // 4*4096*64
    unsigned short* VT = Kb + 4 * 4096 * 64;       // 4*64*4096

    prep_weights<<<768, 256, 0, stream>>>(Wq, Wk, Wv, Wt);
    proj_qkv<<<256, 256, 0, stream>>>(emb, Wt, bq, bk, bv, Qb, Kb, VT);
    attn<<<256, 256, 0, stream>>>(Qb, Kb, VT, out);
}

// Round 2
// 203.976 us; speedup vs baseline: 1.2752x; 1.2752x over previous
//
#include <hip/hip_runtime.h>

#define SEQ  4096
#define DMODEL 1024
#define QTOT 16384   // B*S

typedef __bf16 bf16x8 __attribute__((ext_vector_type(8)));
typedef unsigned short u16x8 __attribute__((ext_vector_type(8)));
typedef float f32x4 __attribute__((ext_vector_type(4)));

// ---------- helpers ----------
static __device__ __forceinline__ unsigned short f2bfbits(float f) {
    unsigned int u = __builtin_bit_cast(unsigned int, f);
    unsigned int lsb = (u >> 16) & 1u;
    u += 0x7fffu + lsb;                      // round-to-nearest-even
    return (unsigned short)(u >> 16);
}

static __device__ __forceinline__ bf16x8 ld_frag(const unsigned short* p) {
    uint4 u = *reinterpret_cast<const uint4*>(p);
    return __builtin_bit_cast(bf16x8, u);
}

// ---------- kernel 1: weights -> bf16 W^T [192][1024] ----------
__global__ void prep_weights(const float* __restrict__ Wq,
                             const float* __restrict__ Wk,
                             const float* __restrict__ Wv,
                             unsigned short* __restrict__ Wt) {
    int i = blockIdx.x * 256 + threadIdx.x;      // 192*1024 total
    int n = i >> 10, k = i & 1023;
    float v;
    if (n < 64)       v = Wq[k * 64 + n];
    else if (n < 128) v = Wk[k * 64 + (n - 64)];
    else              v = Wv[k * 64 + (n - 128)];
    Wt[n * 1024 + k] = f2bfbits(v);
}

// ---------- kernel 2: QKV projection (MFMA bf16, no LDS, no barriers) ----------
// grid 256 blocks x 256 thr; wave = 16 tokens x 192 outs; W frags from L1/L2
__global__ __launch_bounds__(256) void proj_qkv(
        const float* __restrict__ emb, const unsigned short* __restrict__ Wt,
        const float* __restrict__ bq, const float* __restrict__ bk,
        const float* __restrict__ bv,
        unsigned short* __restrict__ Qb, unsigned short* __restrict__ Kb,
        unsigned short* __restrict__ VT) {
    const int tid = threadIdx.x;
    const int w = tid >> 6, lane = tid & 63;
    const int c = lane & 15, qd = lane >> 4;
    const int mbase = blockIdx.x * 64 + w * 16;

    f32x4 acc[12];
#pragma unroll
    for (int i = 0; i < 12; i++) acc[i] = (f32x4){0.f, 0.f, 0.f, 0.f};

    const float* ap = emb + (size_t)(mbase + c) * DMODEL + qd * 8;
    const unsigned short* wp = Wt + c * 1024 + qd * 8;

    float4 ca0 = *reinterpret_cast<const float4*>(ap);
    float4 ca1 = *reinterpret_cast<const float4*>(ap + 4);

    for (int k0 = 0; k0 < DMODEL; k0 += 32) {
        float4 na0, na1;
        if (k0 + 32 < DMODEL) {                    // register prefetch next chunk
            na0 = *reinterpret_cast<const float4*>(ap + k0 + 32);
            na1 = *reinterpret_cast<const float4*>(ap + k0 + 36);
        } else {
            na0 = ca0; na1 = ca1;
        }
        u16x8 at;
        at[0] = f2bfbits(ca0.x); at[1] = f2bfbits(ca0.y);
        at[2] = f2bfbits(ca0.z); at[3] = f2bfbits(ca0.w);
        at[4] = f2bfbits(ca1.x); at[5] = f2bfbits(ca1.y);
        at[6] = f2bfbits(ca1.z); at[7] = f2bfbits(ca1.w);
        bf16x8 af = __builtin_bit_cast(bf16x8, at);

#pragma unroll
        for (int nt = 0; nt < 12; nt++) {
            bf16x8 bfr = ld_frag(wp + nt * 16384 + k0);   // (nt*16+c)*1024 + k0 + qd*8
            acc[nt] = __builtin_amdgcn_mfma_f32_16x16x32_bf16(af, bfr, acc[nt], 0, 0, 0);
        }
        ca0 = na0; ca1 = na1;
    }

#pragma unroll
    for (int nt = 0; nt < 12; nt++) {
        int n = nt * 16 + c;
        float bias = (n < 64) ? bq[n] : (n < 128) ? bk[n - 64] : bv[n - 128];
#pragma unroll
        for (int r = 0; r < 4; r++) {
            int token = mbase + qd * 4 + r;
            unsigned short bits = f2bfbits(acc[nt][r] + bias);
            if (n < 64)        Qb[(size_t)token * 64 + n] = bits;
            else if (n < 128)  Kb[(size_t)token * 64 + (n - 64)] = bits;
            else {
                int bb = token >> 12, s = token & 4095;
                VT[((size_t)bb * 64 + (n - 128)) * SEQ + s] = bits;
            }
        }
    }
}

// ---------- kernel 3: flash attention, no-max softmax, t-split partials ----------
// grid 256*nsplit blocks; blockIdx = split*256 + (b*64 + qblk)
__global__ __launch_bounds__(256) void attn(
        const unsigned short* __restrict__ Qb, const unsigned short* __restrict__ Kb,
        const unsigned short* __restrict__ VT,
        float* __restrict__ accP, float* __restrict__ lP,
        float* __restrict__ outDirect, int tlen) {
    __shared__ __align__(16) unsigned short Kt[64 * 72];    // [t][64k] pad->72
    __shared__ __align__(16) unsigned short Vt[64 * 72];    // [v][64t] pad->72
    __shared__ __align__(16) unsigned short Pl[4][16 * 72]; // per-wave P [q][64t]

    const int tid = threadIdx.x;
    const int w = tid >> 6, lane = tid & 63;
    const int c = lane & 15, qd = lane >> 4;
    const int split = blockIdx.x >> 8;
    const int qblock = blockIdx.x & 255;
    const int b = qblock >> 6;
    const int qbase = (qblock & 63) * 64 + w * 16;
    const int tstart = split * tlen;
    const float kLS = 0.18033688011112042f;  // log2(e)/8

    const unsigned short* Qp = Qb + ((size_t)(b << 12) + qbase + c) * 64 + qd * 8;
    bf16x8 aq0 = ld_frag(Qp);
    bf16x8 aq1 = ld_frag(Qp + 32);

    f32x4 acc[4];
#pragma unroll
    for (int i = 0; i < 4; i++) acc[i] = (f32x4){0.f, 0.f, 0.f, 0.f};
    float l_r[4] = {0.f, 0.f, 0.f, 0.f};

    for (int t0 = tstart; t0 < tstart + tlen; t0 += 64) {
        __syncthreads();
#pragma unroll
        for (int i = 0; i < 2; i++) {            // 512 16B-chunks each for K and V
            int ch = tid + 256 * i;
            int tr = ch >> 3, koff = (ch & 7) * 8;
            *reinterpret_cast<uint4*>(&Kt[tr * 72 + koff]) =
                *reinterpret_cast<const uint4*>(Kb + ((size_t)(b << 12) + t0 + tr) * 64 + koff);
            *reinterpret_cast<uint4*>(&Vt[tr * 72 + koff]) =
                *reinterpret_cast<const uint4*>(VT + ((size_t)b * 64 + tr) * SEQ + t0 + koff);
        }
        __syncthreads();

        // scores: 4 tiles of 16 t  (lane holds q = qd*4+r rows, t col = ts*16+c)
        f32x4 s[4];
#pragma unroll
        for (int ts = 0; ts < 4; ts++) {
            bf16x8 bk0 = ld_frag(&Kt[(ts * 16 + c) * 72 + qd * 8]);
            bf16x8 bk1 = ld_frag(&Kt[(ts * 16 + c) * 72 + 32 + qd * 8]);
            f32x4 z = (f32x4){0.f, 0.f, 0.f, 0.f};
            z = __builtin_amdgcn_mfma_f32_16x16x32_bf16(aq0, bk0, z, 0, 0, 0);
            z = __builtin_amdgcn_mfma_f32_16x16x32_bf16(aq1, bk1, z, 0, 0, 0);
            s[ts] = z;
        }

        // un-shifted softmax numerator (scores are small: |s*scale| < ~3)
        float pv[4][4];
#pragma unroll
        for (int ts = 0; ts < 4; ts++)
#pragma unroll
            for (int r = 0; r < 4; r++)
                pv[ts][r] = __builtin_amdgcn_exp2f(s[ts][r] * kLS);
#pragma unroll
        for (int r = 0; r < 4; r++)
            l_r[r] += pv[0][r] + pv[1][r] + pv[2][r] + pv[3][r];

        // P -> LDS (C-layout to A-layout transform)
#pragma unroll
        for (int ts = 0; ts < 4; ts++)
#pragma unroll
            for (int r = 0; r < 4; r++)
                Pl[w][(qd * 4 + r) * 72 + ts * 16 + c] = f2bfbits(pv[ts][r]);

        bf16x8 ap0 = ld_frag(&Pl[w][c * 72 + qd * 8]);
        bf16x8 ap1 = ld_frag(&Pl[w][c * 72 + 32 + qd * 8]);
#pragma unroll
        for (int nt = 0; nt < 4; nt++) {
            bf16x8 bv0 = ld_frag(&Vt[(nt * 16 + c) * 72 + qd * 8]);
            bf16x8 bv1 = ld_frag(&Vt[(nt * 16 + c) * 72 + 32 + qd * 8]);
            acc[nt] = __builtin_amdgcn_mfma_f32_16x16x32_bf16(ap0, bv0, acc[nt], 0, 0, 0);
            acc[nt] = __builtin_amdgcn_mfma_f32_16x16x32_bf16(ap1, bv1, acc[nt], 0, 0, 0);
        }
    }

    // one-time l reduction across the 16 column lanes (xor 1,2,4,8 stays in quad-group)
#pragma unroll
    for (int off = 1; off < 16; off <<= 1)
#pragma unroll
        for (int r = 0; r < 4; r++) l_r[r] += __shfl_xor(l_r[r], off);

    if (outDirect) {
#pragma unroll
        for (int nt = 0; nt < 4; nt++)
#pragma unroll
            for (int r = 0; r < 4; r++) {
                int q = qbase + qd * 4 + r;
                outDirect[(((size_t)b << 12) + q) * 64 + nt * 16 + c] = acc[nt][r] / l_r[r];
            }
    } else {
#pragma unroll
        for (int nt = 0; nt < 4; nt++)
#pragma unroll
            for (int r = 0; r < 4; r++) {
                size_t q = (size_t)(b << 12) + qbase + qd * 4 + r;
                accP[((size_t)split * QTOT + q) * 64 + nt * 16 + c] = acc[nt][r];
            }
        if (c == 0) {
#pragma unroll
            for (int r = 0; r < 4; r++)
                lP[(size_t)split * QTOT + (b << 12) + qbase + qd * 4 + r] = l_r[r];
        }
    }
}

// ---------- kernel 4: merge t-split partials ----------
__global__ __launch_bounds__(256) void merge_out(
        const float* __restrict__ accP, const float* __restrict__ lP,
        float* __restrict__ out, int ns) {
    int idx = blockIdx.x * 256 + threadIdx.x;   // QTOT*64
    int q = idx >> 6;
    float a = 0.f, l = 0.f;
    for (int s = 0; s < ns; s++) {
        a += accP[(size_t)s * QTOT * 64 + idx];
        l += lP[(size_t)s * QTOT + q];
    }
    out[idx] = a / l;
}

// ---------- launch ----------
extern "C" void kernel_launch(void* const* d_in, const int* in_sizes, int n_in,
                              void* d_out, int out_size, void* d_ws, size_t ws_size,
                              hipStream_t stream) {
    const float* emb = (const float*)d_in[0];
    const float* Wq  = (const float*)d_in[1];
    const float* bq  = (const float*)d_in[2];
    const float* Wk  = (const float*)d_in[3];
    const float* bk  = (const float*)d_in[4];
    const float* Wv  = (const float*)d_in[5];
    const float* bv  = (const float*)d_in[6];
    float* out = (float*)d_out;

    unsigned short* ws = (unsigned short*)d_ws;
    unsigned short* Wt = ws;                       // 192*1024
    unsigned short* Qb = ws + 192 * 1024;          // 4*4096*64
    unsigned short* Kb = Qb + 4 * 4096 * 64;       // 4*4096*64
    unsigned short* VT = Kb + 4 * 4096 * 64;       // 4*64*4096

    size_t base = (size_t)(192 * 1024 + 3 * 4 * 4096 * 64) * 2;   // 6,684,672 B
    size_t per  = (size_t)QTOT * 64 * 4 + (size_t)QTOT * 4;       // acc + l per split

    int ns = 0;
    if (ws_size >= base + 4 * per)      ns = 4;
    else if (ws_size >= base + 2 * per) ns = 2;
    else if (ws_size >= base + per)     ns = 1;

    prep_weights<<<768, 256, 0, stream>>>(Wq, Wk, Wv, Wt);
    proj_qkv<<<256, 256, 0, stream>>>(emb, Wt, bq, bk, bv, Qb, Kb, VT);

    if (ns == 0) {
        attn<<<256, 256, 0, stream>>>(Qb, Kb, VT, nullptr, nullptr, out, SEQ);
    } else {
        float* accP = (float*)((char*)d_ws + base);
        float* lP   = accP + (size_t)ns * QTOT * 64;
        attn<<<256 * ns, 256, 0, stream>>>(Qb, Kb, VT, accP, lP, nullptr, SEQ / ns);
        merge_out<<<(QTOT * 64) / 256, 256, 0, stream>>>(accP, lP, out, ns);
    }
}

// Round 3
// 182.543 us; speedup vs baseline: 1.4249x; 1.1174x over previous
//
#include <hip/hip_runtime.h>

#define SEQ  4096
#define DMODEL 1024
#define QTOT 16384           // B*S
#define NQK (QTOT * 128)     // Q+K partial elements per split
#define NV  (QTOT * 64)      // V partial elements per split

typedef __bf16 bf16x8 __attribute__((ext_vector_type(8)));
typedef unsigned short u16x8 __attribute__((ext_vector_type(8)));
typedef float f32x4 __attribute__((ext_vector_type(4)));

// ---------- helpers ----------
static __device__ __forceinline__ unsigned short f2bfbits(float f) {
    unsigned int u = __builtin_bit_cast(unsigned int, f);
    unsigned int lsb = (u >> 16) & 1u;
    u += 0x7fffu + lsb;                      // round-to-nearest-even
    return (unsigned short)(u >> 16);
}

static __device__ __forceinline__ bf16x8 ld_frag(const unsigned short* p) {
    uint4 u = *reinterpret_cast<const uint4*>(p);
    return __builtin_bit_cast(bf16x8, u);
}

static __device__ __forceinline__ void stp(float* p, float v) { *p = v; }
static __device__ __forceinline__ void stp(unsigned short* p, float v) { *p = f2bfbits(v); }

// ---------- kernel 1: weights -> bf16 W, pre-swizzled into MFMA fragment order ----------
// WtS layout: frag(kc,nt) at ushort offset (kc*12+nt)*512; lane l owns [l*8, l*8+8)
// element j of lane l = W^T[nt*16 + (l&15)][kc*32 + (l>>4)*8 + j]
__global__ void prep_weights(const float* __restrict__ Wq,
                             const float* __restrict__ Wk,
                             const float* __restrict__ Wv,
                             unsigned short* __restrict__ WtS) {
    int o = blockIdx.x * 256 + threadIdx.x;      // 192*1024 total
    int f = o >> 9, q = o & 511;
    int lane = q >> 3, j = q & 7;
    int kc = f / 12, nt = f - kc * 12;
    int n = nt * 16 + (lane & 15);
    int k = kc * 32 + (lane >> 4) * 8 + j;
    float v;
    if (n < 64)       v = Wq[k * 64 + n];
    else if (n < 128) v = Wk[k * 64 + (n - 64)];
    else              v = Wv[k * 64 + (n - 128)];
    WtS[o] = f2bfbits(v);
}

// ---------- kernel 2: QKV projection, K-split=2, partials out ----------
// grid 512 blocks; blockIdx = split*256 + tokenblock; wave = 16 tokens x 192 outs
template <typename T>
__global__ __launch_bounds__(256) void proj_split(
        const float* __restrict__ emb, const unsigned short* __restrict__ WtS,
        T* __restrict__ PQK, T* __restrict__ PV) {
    const int tid = threadIdx.x;
    const int w = tid >> 6, lane = tid & 63;
    const int c = lane & 15, qd = lane >> 4;
    const int split = blockIdx.x >> 8;
    const int tb = blockIdx.x & 255;
    const int mbase = tb * 64 + w * 16;
    const int kbase = split * 512;

    f32x4 acc[12];
#pragma unroll
    for (int i = 0; i < 12; i++) acc[i] = (f32x4){0.f, 0.f, 0.f, 0.f};

    const float* ap = emb + (size_t)(mbase + c) * DMODEL + kbase + qd * 8;
    const unsigned short* wp = WtS + (size_t)(kbase >> 5) * 6144 + lane * 8;

    float4 e0a = *reinterpret_cast<const float4*>(ap);
    float4 e0b = *reinterpret_cast<const float4*>(ap + 4);
    float4 e1a = *reinterpret_cast<const float4*>(ap + 32);
    float4 e1b = *reinterpret_cast<const float4*>(ap + 36);
    bf16x8 wc[12];
#pragma unroll
    for (int nt = 0; nt < 12; nt++) wc[nt] = ld_frag(wp + nt * 512);

#pragma unroll
    for (int s = 0; s < 16; s++) {
        bf16x8 wn[12];
        if (s < 15) {
#pragma unroll
            for (int nt = 0; nt < 12; nt++)
                wn[nt] = ld_frag(wp + (s + 1) * 6144 + nt * 512);
        } else {
#pragma unroll
            for (int nt = 0; nt < 12; nt++) wn[nt] = wc[nt];
        }
        float4 e2a, e2b;
        if (s < 14) {
            e2a = *reinterpret_cast<const float4*>(ap + (s + 2) * 32);
            e2b = *reinterpret_cast<const float4*>(ap + (s + 2) * 32 + 4);
        } else { e2a = e1a; e2b = e1b; }

        u16x8 at;
        at[0] = f2bfbits(e0a.x); at[1] = f2bfbits(e0a.y);
        at[2] = f2bfbits(e0a.z); at[3] = f2bfbits(e0a.w);
        at[4] = f2bfbits(e0b.x); at[5] = f2bfbits(e0b.y);
        at[6] = f2bfbits(e0b.z); at[7] = f2bfbits(e0b.w);
        bf16x8 af = __builtin_bit_cast(bf16x8, at);

#pragma unroll
        for (int nt = 0; nt < 12; nt++)
            acc[nt] = __builtin_amdgcn_mfma_f32_16x16x32_bf16(af, wc[nt], acc[nt], 0, 0, 0);

        e0a = e1a; e0b = e1b; e1a = e2a; e1b = e2b;
#pragma unroll
        for (int nt = 0; nt < 12; nt++) wc[nt] = wn[nt];
    }

#pragma unroll
    for (int nt = 0; nt < 12; nt++) {
        int n = nt * 16 + c;
#pragma unroll
        for (int r = 0; r < 4; r++) {
            int token = mbase + qd * 4 + r;
            if (n < 128)
                stp(&PQK[(size_t)split * NQK + (size_t)token * 128 + n], acc[nt][r]);
            else {
                int bb = token >> 12, s = token & 4095, v = n - 128;
                stp(&PV[(size_t)split * NV + ((size_t)bb << 18) + (v << 12) + s], acc[nt][r]);
            }
        }
    }
}

// ---------- kernel 2b: merge proj partials (+bias, ->bf16, V transposed) ----------
template <typename T>
__global__ __launch_bounds__(256) void merge_proj(
        const T* __restrict__ PQK, const T* __restrict__ PV,
        const float* __restrict__ bq, const float* __restrict__ bk,
        const float* __restrict__ bv,
        unsigned short* __restrict__ Qb, unsigned short* __restrict__ Kb,
        unsigned short* __restrict__ VT) {
    int idx4 = (blockIdx.x * 256 + threadIdx.x) * 4;
    float s[4];
    if (idx4 < NQK) {
        int token = idx4 >> 7, n = idx4 & 127;
#pragma unroll
        for (int j = 0; j < 4; j++) s[j] = 0.f;
#pragma unroll
        for (int kz = 0; kz < 2; kz++) {
            if constexpr (sizeof(T) == 4) {
                float4 v = *reinterpret_cast<const float4*>(&PQK[(size_t)kz * NQK + idx4]);
                s[0] += v.x; s[1] += v.y; s[2] += v.z; s[3] += v.w;
            } else {
                ushort4 v = *reinterpret_cast<const ushort4*>(&PQK[(size_t)kz * NQK + idx4]);
                s[0] += __builtin_bit_cast(float, (unsigned int)v.x << 16);
                s[1] += __builtin_bit_cast(float, (unsigned int)v.y << 16);
                s[2] += __builtin_bit_cast(float, (unsigned int)v.z << 16);
                s[3] += __builtin_bit_cast(float, (unsigned int)v.w << 16);
            }
        }
        const float* bias = (n < 64) ? bq + n : bk + (n - 64);
        unsigned short* dst = (n < 64) ? Qb + (size_t)token * 64 + n
                                       : Kb + (size_t)token * 64 + (n - 64);
#pragma unroll
        for (int j = 0; j < 4; j++) dst[j] = f2bfbits(s[j] + bias[j]);
    } else {
        int j0 = idx4 - NQK;                      // [b][v][s] flattened
        int v = (j0 >> 12) & 63;
        float bias = bv[v];
#pragma unroll
        for (int j = 0; j < 4; j++) s[j] = bias;
#pragma unroll
        for (int kz = 0; kz < 2; kz++) {
            if constexpr (sizeof(T) == 4) {
                float4 vv = *reinterpret_cast<const float4*>(&PV[(size_t)kz * NV + j0]);
                s[0] += vv.x; s[1] += vv.y; s[2] += vv.z; s[3] += vv.w;
            } else {
                ushort4 vv = *reinterpret_cast<const ushort4*>(&PV[(size_t)kz * NV + j0]);
                s[0] += __builtin_bit_cast(float, (unsigned int)vv.x << 16);
                s[1] += __builtin_bit_cast(float, (unsigned int)vv.y << 16);
                s[2] += __builtin_bit_cast(float, (unsigned int)vv.z << 16);
                s[3] += __builtin_bit_cast(float, (unsigned int)vv.w << 16);
            }
        }
#pragma unroll
        for (int j = 0; j < 4; j++) VT[j0 + j] = f2bfbits(s[j]);
    }
}

// ---------- kernel 2-alt: direct proj (fallback when ws is tiny) ----------
__global__ __launch_bounds__(256) void proj_direct(
        const float* __restrict__ emb, const unsigned short* __restrict__ WtS,
        const float* __restrict__ bq, const float* __restrict__ bk,
        const float* __restrict__ bv,
        unsigned short* __restrict__ Qb, unsigned short* __restrict__ Kb,
        unsigned short* __restrict__ VT) {
    const int tid = threadIdx.x;
    const int w = tid >> 6, lane = tid & 63;
    const int c = lane & 15, qd = lane >> 4;
    const int mbase = blockIdx.x * 64 + w * 16;

    f32x4 acc[12];
#pragma unroll
    for (int i = 0; i < 12; i++) acc[i] = (f32x4){0.f, 0.f, 0.f, 0.f};

    const float* ap = emb + (size_t)(mbase + c) * DMODEL + qd * 8;
    const unsigned short* wp = WtS + lane * 8;

    float4 e0a = *reinterpret_cast<const float4*>(ap);
    float4 e0b = *reinterpret_cast<const float4*>(ap + 4);
    float4 e1a = *reinterpret_cast<const float4*>(ap + 32);
    float4 e1b = *reinterpret_cast<const float4*>(ap + 36);
    bf16x8 wc[12];
#pragma unroll
    for (int nt = 0; nt < 12; nt++) wc[nt] = ld_frag(wp + nt * 512);

#pragma unroll 4
    for (int s = 0; s < 32; s++) {
        bf16x8 wn[12];
        if (s < 31) {
#pragma unroll
            for (int nt = 0; nt < 12; nt++)
                wn[nt] = ld_frag(wp + (s + 1) * 6144 + nt * 512);
        } else {
#pragma unroll
            for (int nt = 0; nt < 12; nt++) wn[nt] = wc[nt];
        }
        float4 e2a, e2b;
        if (s < 30) {
            e2a = *reinterpret_cast<const float4*>(ap + (s + 2) * 32);
            e2b = *reinterpret_cast<const float4*>(ap + (s + 2) * 32 + 4);
        } else { e2a = e1a; e2b = e1b; }

        u16x8 at;
        at[0] = f2bfbits(e0a.x); at[1] = f2bfbits(e0a.y);
        at[2] = f2bfbits(e0a.z); at[3] = f2bfbits(e0a.w);
        at[4] = f2bfbits(e0b.x); at[5] = f2bfbits(e0b.y);
        at[6] = f2bfbits(e0b.z); at[7] = f2bfbits(e0b.w);
        bf16x8 af = __builtin_bit_cast(bf16x8, at);

#pragma unroll
        for (int nt = 0; nt < 12; nt++)
            acc[nt] = __builtin_amdgcn_mfma_f32_16x16x32_bf16(af, wc[nt], acc[nt], 0, 0, 0);

        e0a = e1a; e0b = e1b; e1a = e2a; e1b = e2b;
#pragma unroll
        for (int nt = 0; nt < 12; nt++) wc[nt] = wn[nt];
    }

#pragma unroll
    for (int nt = 0; nt < 12; nt++) {
        int n = nt * 16 + c;
        float bias = (n < 64) ? bq[n] : (n < 128) ? bk[n - 64] : bv[n - 128];
#pragma unroll
        for (int r = 0; r < 4; r++) {
            int token = mbase + qd * 4 + r;
            unsigned short bits = f2bfbits(acc[nt][r] + bias);
            if (n < 64)        Qb[(size_t)token * 64 + n] = bits;
            else if (n < 128)  Kb[(size_t)token * 64 + (n - 64)] = bits;
            else {
                int bb = token >> 12, ss = token & 4095;
                VT[((size_t)bb * 64 + (n - 128)) * SEQ + ss] = bits;
            }
        }
    }
}

// ---------- kernel 3: flash attention, no-max softmax, t-split, XCD-swizzled ----------
// blockIdx = qblk*(ns*4) + g where g = split*4 + b  -> (b,split) group pins to one XCD
__global__ __launch_bounds__(256) void attn(
        const unsigned short* __restrict__ Qb, const unsigned short* __restrict__ Kb,
        const unsigned short* __restrict__ VT,
        float* __restrict__ accP, float* __restrict__ lP,
        float* __restrict__ outDirect, int tlen, int gshift) {
    __shared__ __align__(16) unsigned short Kt[64 * 72];    // [t][64k] pad->72
    __shared__ __align__(16) unsigned short Vt[64 * 72];    // [v][64t] pad->72
    __shared__ __align__(16) unsigned short Pl[4][16 * 72]; // per-wave P [q][64t]

    const int tid = threadIdx.x;
    const int w = tid >> 6, lane = tid & 63;
    const int c = lane & 15, qd = lane >> 4;
    const int g = blockIdx.x & ((1 << gshift) - 1);
    const int qblk = blockIdx.x >> gshift;
    const int split = g >> 2, b = g & 3;
    const int qbase = qblk * 64 + w * 16;
    const int tstart = split * tlen;
    const float kLS = 0.18033688011112042f;  // log2(e)/8

    const unsigned short* Qp = Qb + ((size_t)(b << 12) + qbase + c) * 64 + qd * 8;
    bf16x8 aq0 = ld_frag(Qp);
    bf16x8 aq1 = ld_frag(Qp + 32);

    f32x4 acc[4];
#pragma unroll
    for (int i = 0; i < 4; i++) acc[i] = (f32x4){0.f, 0.f, 0.f, 0.f};
    float l_r[4] = {0.f, 0.f, 0.f, 0.f};

    for (int t0 = tstart; t0 < tstart + tlen; t0 += 64) {
        __syncthreads();
#pragma unroll
        for (int i = 0; i < 2; i++) {            // 512 16B-chunks each for K and V
            int ch = tid + 256 * i;
            int tr = ch >> 3, koff = (ch & 7) * 8;
            *reinterpret_cast<uint4*>(&Kt[tr * 72 + koff]) =
                *reinterpret_cast<const uint4*>(Kb + ((size_t)(b << 12) + t0 + tr) * 64 + koff);
            *reinterpret_cast<uint4*>(&Vt[tr * 72 + koff]) =
                *reinterpret_cast<const uint4*>(VT + ((size_t)b * 64 + tr) * SEQ + t0 + koff);
        }
        __syncthreads();

        f32x4 s[4];
#pragma unroll
        for (int ts = 0; ts < 4; ts++) {
            bf16x8 bk0 = ld_frag(&Kt[(ts * 16 + c) * 72 + qd * 8]);
            bf16x8 bk1 = ld_frag(&Kt[(ts * 16 + c) * 72 + 32 + qd * 8]);
            f32x4 z = (f32x4){0.f, 0.f, 0.f, 0.f};
            z = __builtin_amdgcn_mfma_f32_16x16x32_bf16(aq0, bk0, z, 0, 0, 0);
            z = __builtin_amdgcn_mfma_f32_16x16x32_bf16(aq1, bk1, z, 0, 0, 0);
            s[ts] = z;
        }

        float pv[4][4];
#pragma unroll
        for (int ts = 0; ts < 4; ts++)
#pragma unroll
            for (int r = 0; r < 4; r++)
                pv[ts][r] = __builtin_amdgcn_exp2f(s[ts][r] * kLS);
#pragma unroll
        for (int r = 0; r < 4; r++)
            l_r[r] += pv[0][r] + pv[1][r] + pv[2][r] + pv[3][r];

#pragma unroll
        for (int ts = 0; ts < 4; ts++)
#pragma unroll
            for (int r = 0; r < 4; r++)
                Pl[w][(qd * 4 + r) * 72 + ts * 16 + c] = f2bfbits(pv[ts][r]);

        bf16x8 ap0 = ld_frag(&Pl[w][c * 72 + qd * 8]);
        bf16x8 ap1 = ld_frag(&Pl[w][c * 72 + 32 + qd * 8]);
#pragma unroll
        for (int nt = 0; nt < 4; nt++) {
            bf16x8 bv0 = ld_frag(&Vt[(nt * 16 + c) * 72 + qd * 8]);
            bf16x8 bv1 = ld_frag(&Vt[(nt * 16 + c) * 72 + 32 + qd * 8]);
            acc[nt] = __builtin_amdgcn_mfma_f32_16x16x32_bf16(ap0, bv0, acc[nt], 0, 0, 0);
            acc[nt] = __builtin_amdgcn_mfma_f32_16x16x32_bf16(ap1, bv1, acc[nt], 0, 0, 0);
        }
    }

#pragma unroll
    for (int off = 1; off < 16; off <<= 1)
#pragma unroll
        for (int r = 0; r < 4; r++) l_r[r] += __shfl_xor(l_r[r], off);

    if (outDirect) {
#pragma unroll
        for (int nt = 0; nt < 4; nt++)
#pragma unroll
            for (int r = 0; r < 4; r++) {
                int q = qbase + qd * 4 + r;
                outDirect[(((size_t)b << 12) + q) * 64 + nt * 16 + c] = acc[nt][r] / l_r[r];
            }
    } else {
#pragma unroll
        for (int nt = 0; nt < 4; nt++)
#pragma unroll
            for (int r = 0; r < 4; r++) {
                size_t q = (size_t)(b << 12) + qbase + qd * 4 + r;
                accP[((size_t)split * QTOT + q) * 64 + nt * 16 + c] = acc[nt][r];
            }
        if (c == 0) {
#pragma unroll
            for (int r = 0; r < 4; r++)
                lP[(size_t)split * QTOT + (b << 12) + qbase + qd * 4 + r] = l_r[r];
        }
    }
}

// ---------- kernel 4: merge attn t-split partials ----------
__global__ __launch_bounds__(256) void merge_out(
        const float* __restrict__ accP, const float* __restrict__ lP,
        float* __restrict__ out, int ns) {
    int idx = blockIdx.x * 256 + threadIdx.x;   // QTOT*64
    int q = idx >> 6;
    float a = 0.f, l = 0.f;
    for (int s = 0; s < ns; s++) {
        a += accP[(size_t)s * QTOT * 64 + idx];
        l += lP[(size_t)s * QTOT + q];
    }
    out[idx] = a / l;
}

// ---------- launch ----------
extern "C" void kernel_launch(void* const* d_in, const int* in_sizes, int n_in,
                              void* d_out, int out_size, void* d_ws, size_t ws_size,
                              hipStream_t stream) {
    const float* emb = (const float*)d_in[0];
    const float* Wq  = (const float*)d_in[1];
    const float* bq  = (const float*)d_in[2];
    const float* Wk  = (const float*)d_in[3];
    const float* bk  = (const float*)d_in[4];
    const float* Wv  = (const float*)d_in[5];
    const float* bv  = (const float*)d_in[6];
    float* out = (float*)d_out;

    unsigned short* ws = (unsigned short*)d_ws;
    unsigned short* WtS = ws;                      // 192*1024
    unsigned short* Qb = ws + 192 * 1024;          // QTOT*64
    unsigned short* Kb = Qb + QTOT * 64;
    unsigned short* VT = Kb + QTOT * 64;
    char* region = (char*)(VT + QTOT * 64);        // byte offset 6,684,672
    size_t avail = (ws_size > 6684672) ? ws_size - 6684672 : 0;

    // proj tier: fp32 split2 (25.2 MB) > bf16 split2 (12.6 MB) > direct
    int projMode = (avail >= (size_t)2 * (NQK + NV) * 4) ? 2
                 : (avail >= (size_t)2 * (NQK + NV) * 2) ? 1 : 0;
    // attn splits (region aliased; proj partials dead before attn runs)
    size_t per = (size_t)QTOT * 64 * 4 + (size_t)QTOT * 4;
    int ns = (avail >= 4 * per) ? 4 : (avail >= 2 * per) ? 2 : (avail >= per) ? 1 : 0;

    prep_weights<<<768, 256, 0, stream>>>(Wq, Wk, Wv, WtS);

    if (projMode == 2) {
        float* PQKp = (float*)region;
        float* PVp  = PQKp + (size_t)2 * NQK;
        proj_split<float><<<512, 256, 0, stream>>>(emb, WtS, PQKp, PVp);
        merge_proj<float><<<3072, 256, 0, stream>>>(PQKp, PVp, bq, bk, bv, Qb, Kb, VT);
    } else if (projMode == 1) {
        unsigned short* PQKp = (unsigned short*)region;
        unsigned short* PVp  = PQKp + (size_t)2 * NQK;
        proj_split<unsigned short><<<512, 256, 0, stream>>>(emb, WtS, PQKp, PVp);
        merge_proj<unsigned short><<<3072, 256, 0, stream>>>(PQKp, PVp, bq, bk, bv, Qb, Kb, VT);
    } else {
        proj_direct<<<256, 256, 0, stream>>>(emb, WtS, bq, bk, bv, Qb, Kb, VT);
    }

    if (ns > 0) {
        float* accP = (float*)region;              // alias: proj partials are dead now
        float* lP   = accP + (size_t)ns * QTOT * 64;
        int gshift = (ns == 4) ? 4 : (ns == 2) ? 3 : 2;
        attn<<<256 * ns, 256, 0, stream>>>(Qb, Kb, VT, accP, lP, nullptr, SEQ / ns, gshift);
        merge_out<<<(QTOT * 64) / 256, 256, 0, stream>>>(accP, lP, out, ns);
    } else {
        attn<<<256, 256, 0, stream>>>(Qb, Kb, VT, nullptr, nullptr, out, SEQ, 2);
    }
}

// Round 4
// 173.320 us; speedup vs baseline: 1.5008x; 1.0532x over previous
//
#include <hip/hip_runtime.h>

#define SEQ  4096
#define DMODEL 1024
#define QTOT 16384           // B*S
#define NQK (QTOT * 128)     // Q+K partial elements per split
#define NV  (QTOT * 64)      // V partial elements per split
#define QSCALE 0.18033688011112042f   // (1/sqrt(64)) * log2(e), folded into Q

typedef __bf16 bf16x8 __attribute__((ext_vector_type(8)));
typedef unsigned short u16x8 __attribute__((ext_vector_type(8)));
typedef float f32x4 __attribute__((ext_vector_type(4)));

// ---------- helpers ----------
static __device__ __forceinline__ unsigned short f2bfbits(float f) {
    unsigned int u = __builtin_bit_cast(unsigned int, f);
    unsigned int lsb = (u >> 16) & 1u;
    u += 0x7fffu + lsb;                      // round-to-nearest-even
    return (unsigned short)(u >> 16);
}

static __device__ __forceinline__ bf16x8 ld_frag(const unsigned short* p) {
    uint4 u = *reinterpret_cast<const uint4*>(p);
    return __builtin_bit_cast(bf16x8, u);
}

static __device__ __forceinline__ void stp(float* p, float v) { *p = v; }
static __device__ __forceinline__ void stp(unsigned short* p, float v) { *p = f2bfbits(v); }

// ---------- kernel 1: weights -> bf16, pre-swizzled into MFMA fragment order ----------
__global__ void prep_weights(const float* __restrict__ Wq,
                             const float* __restrict__ Wk,
                             const float* __restrict__ Wv,
                             unsigned short* __restrict__ WtS) {
    int o = blockIdx.x * 256 + threadIdx.x;      // 192*1024 total
    int f = o >> 9, q = o & 511;
    int lane = q >> 3, j = q & 7;
    int kc = f / 12, nt = f - kc * 12;
    int n = nt * 16 + (lane & 15);
    int k = kc * 32 + (lane >> 4) * 8 + j;
    float v;
    if (n < 64)       v = Wq[k * 64 + n];
    else if (n < 128) v = Wk[k * 64 + (n - 64)];
    else              v = Wv[k * 64 + (n - 128)];
    WtS[o] = f2bfbits(v);
}

// ---------- kernel 2: QKV projection, K-split=2, partials out ----------
template <typename T>
__global__ __launch_bounds__(256) void proj_split(
        const float* __restrict__ emb, const unsigned short* __restrict__ WtS,
        T* __restrict__ PQK, T* __restrict__ PV) {
    const int tid = threadIdx.x;
    const int w = tid >> 6, lane = tid & 63;
    const int c = lane & 15, qd = lane >> 4;
    const int split = blockIdx.x >> 8;
    const int tb = blockIdx.x & 255;
    const int mbase = tb * 64 + w * 16;
    const int kbase = split * 512;

    f32x4 acc[12];
#pragma unroll
    for (int i = 0; i < 12; i++) acc[i] = (f32x4){0.f, 0.f, 0.f, 0.f};

    const float* ap = emb + (size_t)(mbase + c) * DMODEL + kbase + qd * 8;
    const unsigned short* wp = WtS + (size_t)(kbase >> 5) * 6144 + lane * 8;

    float4 e0a = *reinterpret_cast<const float4*>(ap);
    float4 e0b = *reinterpret_cast<const float4*>(ap + 4);
    float4 e1a = *reinterpret_cast<const float4*>(ap + 32);
    float4 e1b = *reinterpret_cast<const float4*>(ap + 36);
    bf16x8 wc[12];
#pragma unroll
    for (int nt = 0; nt < 12; nt++) wc[nt] = ld_frag(wp + nt * 512);

#pragma unroll
    for (int s = 0; s < 16; s++) {
        bf16x8 wn[12];
        if (s < 15) {
#pragma unroll
            for (int nt = 0; nt < 12; nt++)
                wn[nt] = ld_frag(wp + (s + 1) * 6144 + nt * 512);
        } else {
#pragma unroll
            for (int nt = 0; nt < 12; nt++) wn[nt] = wc[nt];
        }
        float4 e2a, e2b;
        if (s < 14) {
            e2a = *reinterpret_cast<const float4*>(ap + (s + 2) * 32);
            e2b = *reinterpret_cast<const float4*>(ap + (s + 2) * 32 + 4);
        } else { e2a = e1a; e2b = e1b; }

        u16x8 at;
        at[0] = f2bfbits(e0a.x); at[1] = f2bfbits(e0a.y);
        at[2] = f2bfbits(e0a.z); at[3] = f2bfbits(e0a.w);
        at[4] = f2bfbits(e0b.x); at[5] = f2bfbits(e0b.y);
        at[6] = f2bfbits(e0b.z); at[7] = f2bfbits(e0b.w);
        bf16x8 af = __builtin_bit_cast(bf16x8, at);

#pragma unroll
        for (int nt = 0; nt < 12; nt++)
            acc[nt] = __builtin_amdgcn_mfma_f32_16x16x32_bf16(af, wc[nt], acc[nt], 0, 0, 0);

        e0a = e1a; e0b = e1b; e1a = e2a; e1b = e2b;
#pragma unroll
        for (int nt = 0; nt < 12; nt++) wc[nt] = wn[nt];
    }

#pragma unroll
    for (int nt = 0; nt < 12; nt++) {
        int n = nt * 16 + c;
#pragma unroll
        for (int r = 0; r < 4; r++) {
            int token = mbase + qd * 4 + r;
            if (n < 128)
                stp(&PQK[(size_t)split * NQK + (size_t)token * 128 + n], acc[nt][r]);
            else {
                int bb = token >> 12, s = token & 4095, v = n - 128;
                stp(&PV[(size_t)split * NV + ((size_t)bb << 18) + (v << 12) + s], acc[nt][r]);
            }
        }
    }
}

// ---------- kernel 2b: merge proj partials (+bias, Q pre-scaled, ->bf16) ----------
template <typename T>
__global__ __launch_bounds__(256) void merge_proj(
        const T* __restrict__ PQK, const T* __restrict__ PV,
        const float* __restrict__ bq, const float* __restrict__ bk,
        const float* __restrict__ bv,
        unsigned short* __restrict__ Qb, unsigned short* __restrict__ Kb,
        unsigned short* __restrict__ VT) {
    int idx4 = (blockIdx.x * 256 + threadIdx.x) * 4;
    float s[4];
    if (idx4 < NQK) {
        int token = idx4 >> 7, n = idx4 & 127;
#pragma unroll
        for (int j = 0; j < 4; j++) s[j] = 0.f;
#pragma unroll
        for (int kz = 0; kz < 2; kz++) {
            if constexpr (sizeof(T) == 4) {
                float4 v = *reinterpret_cast<const float4*>(&PQK[(size_t)kz * NQK + idx4]);
                s[0] += v.x; s[1] += v.y; s[2] += v.z; s[3] += v.w;
            } else {
                ushort4 v = *reinterpret_cast<const ushort4*>(&PQK[(size_t)kz * NQK + idx4]);
                s[0] += __builtin_bit_cast(float, (unsigned int)v.x << 16);
                s[1] += __builtin_bit_cast(float, (unsigned int)v.y << 16);
                s[2] += __builtin_bit_cast(float, (unsigned int)v.z << 16);
                s[3] += __builtin_bit_cast(float, (unsigned int)v.w << 16);
            }
        }
        bool isQ = (n < 64);
        const float* bias = isQ ? bq + n : bk + (n - 64);
        float fac = isQ ? QSCALE : 1.0f;
        unsigned short* dst = isQ ? Qb + (size_t)token * 64 + n
                                  : Kb + (size_t)token * 64 + (n - 64);
#pragma unroll
        for (int j = 0; j < 4; j++) dst[j] = f2bfbits((s[j] + bias[j]) * fac);
    } else {
        int j0 = idx4 - NQK;                      // [b][v][s] flattened
        int v = (j0 >> 12) & 63;
        float bias = bv[v];
#pragma unroll
        for (int j = 0; j < 4; j++) s[j] = bias;
#pragma unroll
        for (int kz = 0; kz < 2; kz++) {
            if constexpr (sizeof(T) == 4) {
                float4 vv = *reinterpret_cast<const float4*>(&PV[(size_t)kz * NV + j0]);
                s[0] += vv.x; s[1] += vv.y; s[2] += vv.z; s[3] += vv.w;
            } else {
                ushort4 vv = *reinterpret_cast<const ushort4*>(&PV[(size_t)kz * NV + j0]);
                s[0] += __builtin_bit_cast(float, (unsigned int)vv.x << 16);
                s[1] += __builtin_bit_cast(float, (unsigned int)vv.y << 16);
                s[2] += __builtin_bit_cast(float, (unsigned int)vv.z << 16);
                s[3] += __builtin_bit_cast(float, (unsigned int)vv.w << 16);
            }
        }
#pragma unroll
        for (int j = 0; j < 4; j++) VT[j0 + j] = f2bfbits(s[j]);
    }
}

// ---------- kernel 2-alt: direct proj (fallback when ws is tiny) ----------
__global__ __launch_bounds__(256) void proj_direct(
        const float* __restrict__ emb, const unsigned short* __restrict__ WtS,
        const float* __restrict__ bq, const float* __restrict__ bk,
        const float* __restrict__ bv,
        unsigned short* __restrict__ Qb, unsigned short* __restrict__ Kb,
        unsigned short* __restrict__ VT) {
    const int tid = threadIdx.x;
    const int w = tid >> 6, lane = tid & 63;
    const int c = lane & 15, qd = lane >> 4;
    const int mbase = blockIdx.x * 64 + w * 16;

    f32x4 acc[12];
#pragma unroll
    for (int i = 0; i < 12; i++) acc[i] = (f32x4){0.f, 0.f, 0.f, 0.f};

    const float* ap = emb + (size_t)(mbase + c) * DMODEL + qd * 8;
    const unsigned short* wp = WtS + lane * 8;

    float4 e0a = *reinterpret_cast<const float4*>(ap);
    float4 e0b = *reinterpret_cast<const float4*>(ap + 4);
    float4 e1a = *reinterpret_cast<const float4*>(ap + 32);
    float4 e1b = *reinterpret_cast<const float4*>(ap + 36);
    bf16x8 wc[12];
#pragma unroll
    for (int nt = 0; nt < 12; nt++) wc[nt] = ld_frag(wp + nt * 512);

#pragma unroll 4
    for (int s = 0; s < 32; s++) {
        bf16x8 wn[12];
        if (s < 31) {
#pragma unroll
            for (int nt = 0; nt < 12; nt++)
                wn[nt] = ld_frag(wp + (s + 1) * 6144 + nt * 512);
        } else {
#pragma unroll
            for (int nt = 0; nt < 12; nt++) wn[nt] = wc[nt];
        }
        float4 e2a, e2b;
        if (s < 30) {
            e2a = *reinterpret_cast<const float4*>(ap + (s + 2) * 32);
            e2b = *reinterpret_cast<const float4*>(ap + (s + 2) * 32 + 4);
        } else { e2a = e1a; e2b = e1b; }

        u16x8 at;
        at[0] = f2bfbits(e0a.x); at[1] = f2bfbits(e0a.y);
        at[2] = f2bfbits(e0a.z); at[3] = f2bfbits(e0a.w);
        at[4] = f2bfbits(e0b.x); at[5] = f2bfbits(e0b.y);
        at[6] = f2bfbits(e0b.z); at[7] = f2bfbits(e0b.w);
        bf16x8 af = __builtin_bit_cast(bf16x8, at);

#pragma unroll
        for (int nt = 0; nt < 12; nt++)
            acc[nt] = __builtin_amdgcn_mfma_f32_16x16x32_bf16(af, wc[nt], acc[nt], 0, 0, 0);

        e0a = e1a; e0b = e1b; e1a = e2a; e1b = e2b;
#pragma unroll
        for (int nt = 0; nt < 12; nt++) wc[nt] = wn[nt];
    }

#pragma unroll
    for (int nt = 0; nt < 12; nt++) {
        int n = nt * 16 + c;
        float bias = (n < 64) ? bq[n] : (n < 128) ? bk[n - 64] : bv[n - 128];
        float fac = (n < 64) ? QSCALE : 1.0f;
#pragma unroll
        for (int r = 0; r < 4; r++) {
            int token = mbase + qd * 4 + r;
            unsigned short bits = f2bfbits((acc[nt][r] + bias) * fac);
            if (n < 64)        Qb[(size_t)token * 64 + n] = bits;
            else if (n < 128)  Kb[(size_t)token * 64 + (n - 64)] = bits;
            else {
                int bb = token >> 12, ss = token & 4095;
                VT[((size_t)bb * 64 + (n - 128)) * SEQ + ss] = bits;
            }
        }
    }
}

// ---------- kernel 3: barrier-free flash attention ----------
// grid 256 blocks (4b x 64 q-blocks, XCD-pinned by b); 512 thr = 8 waves.
// Block owns 64 q-rows x full t. Wave w owns t-slice [w*512, w*512+512).
// K/V B-fragments loaded DIRECTLY from global (already fragment-shaped).
// End: LDS tree-reduction over the 8 t-slices, then out = acc / l.
__global__ __launch_bounds__(512, 2) void attn(
        const unsigned short* __restrict__ Qb, const unsigned short* __restrict__ Kb,
        const unsigned short* __restrict__ VT, float* __restrict__ out) {
    __shared__ __align__(16) unsigned short Pl[8][64 * 72];  // per-wave P [q][t] (also aliased as reduce buf)
    __shared__ float l_all[8][64];

    const int tid = threadIdx.x;
    const int w = tid >> 6, lane = tid & 63;
    const int c = lane & 15, qd = lane >> 4;
    // XCD pinning: blockIdx%8 = b*2 + (qblk&1)
    const int g3 = blockIdx.x & 7;
    const int b = g3 >> 1;
    const int qblk = ((blockIdx.x >> 3) << 1) | (g3 & 1);
    const int qbase = qblk * 64;
    const int tstart = w * 512;

    // Q A-fragments (same for all 8 waves -> L1 broadcast), pre-scaled by QSCALE
    bf16x8 aq0[4], aq1[4];
#pragma unroll
    for (int qs = 0; qs < 4; qs++) {
        const unsigned short* Qp = Qb + ((size_t)(b << 12) + qbase + qs * 16 + c) * 64 + qd * 8;
        aq0[qs] = ld_frag(Qp);
        aq1[qs] = ld_frag(Qp + 32);
    }

    f32x4 acc[16];                               // [qsub][nt]
#pragma unroll
    for (int i = 0; i < 16; i++) acc[i] = (f32x4){0.f, 0.f, 0.f, 0.f};
    float lsum[4][4];                            // [qsub][r] per-lane partial
#pragma unroll
    for (int qs = 0; qs < 4; qs++)
#pragma unroll
        for (int r = 0; r < 4; r++) lsum[qs][r] = 0.f;

    unsigned short* myP = &Pl[w][0];

#pragma unroll 2
    for (int it = 0; it < 8; it++) {
        const int t0 = tstart + it * 64;
        const unsigned short* Kt = Kb + ((size_t)(b << 12) + t0) * 64;

        // K B-fragments straight from global
        bf16x8 bk0[4], bk1[4];
#pragma unroll
        for (int ts = 0; ts < 4; ts++) {
            bk0[ts] = ld_frag(Kt + (ts * 16 + c) * 64 + qd * 8);
            bk1[ts] = ld_frag(Kt + (ts * 16 + c) * 64 + 32 + qd * 8);
        }

        // scores -> exp2 -> P into per-wave LDS (no barrier)
#pragma unroll
        for (int qs = 0; qs < 4; qs++) {
            f32x4 sc[4];
#pragma unroll
            for (int ts = 0; ts < 4; ts++) {
                f32x4 z = (f32x4){0.f, 0.f, 0.f, 0.f};
                z = __builtin_amdgcn_mfma_f32_16x16x32_bf16(aq0[qs], bk0[ts], z, 0, 0, 0);
                z = __builtin_amdgcn_mfma_f32_16x16x32_bf16(aq1[qs], bk1[ts], z, 0, 0, 0);
                sc[ts] = z;
            }
#pragma unroll
            for (int ts = 0; ts < 4; ts++)
#pragma unroll
                for (int r = 0; r < 4; r++) {
                    float p = __builtin_amdgcn_exp2f(sc[ts][r]);   // scale folded into Q
                    lsum[qs][r] += p;
                    myP[(qs * 16 + qd * 4 + r) * 72 + ts * 16 + c] = f2bfbits(p);
                }
        }

        // V B-fragments straight from global (VT is [b][v][t])
        bf16x8 bv0[4], bv1[4];
#pragma unroll
        for (int nt = 0; nt < 4; nt++) {
            const unsigned short* Vp = VT + (((size_t)b * 64 + nt * 16 + c) << 12) + t0 + qd * 8;
            bv0[nt] = ld_frag(Vp);
            bv1[nt] = ld_frag(Vp + 32);
        }

        // P A-fragments (same-wave LDS readback; compiler inserts lgkmcnt)
#pragma unroll
        for (int qs = 0; qs < 4; qs++) {
            bf16x8 ap0 = ld_frag(&myP[(qs * 16 + c) * 72 + qd * 8]);
            bf16x8 ap1 = ld_frag(&myP[(qs * 16 + c) * 72 + 32 + qd * 8]);
#pragma unroll
            for (int nt = 0; nt < 4; nt++) {
                acc[qs * 4 + nt] = __builtin_amdgcn_mfma_f32_16x16x32_bf16(ap0, bv0[nt], acc[qs * 4 + nt], 0, 0, 0);
                acc[qs * 4 + nt] = __builtin_amdgcn_mfma_f32_16x16x32_bf16(ap1, bv1[nt], acc[qs * 4 + nt], 0, 0, 0);
            }
        }
    }

    // per-wave row-sum reduction across the 16 column lanes
#pragma unroll
    for (int off = 1; off < 16; off <<= 1)
#pragma unroll
        for (int qs = 0; qs < 4; qs++)
#pragma unroll
            for (int r = 0; r < 4; r++) lsum[qs][r] += __shfl_xor(lsum[qs][r], off);
    if (c == 0) {
#pragma unroll
        for (int qs = 0; qs < 4; qs++)
#pragma unroll
            for (int r = 0; r < 4; r++)
                l_all[w][qs * 16 + qd * 4 + r] = lsum[qs][r];
    }

    // tree-reduce acc over 8 waves; reduce buffer aliases Pl (slot = 17408 B)
    float* red = (float*)&Pl[0][0];
    __syncthreads();                              // all main loops + l writes done
    if (w >= 4) {
        float* rp = red + (w - 4) * 4352 + lane * 68;
#pragma unroll
        for (int i = 0; i < 16; i++) *reinterpret_cast<f32x4*>(rp + i * 4) = acc[i];
    }
    __syncthreads();
    if (w < 4) {
        float* rp = red + w * 4352 + lane * 68;
#pragma unroll
        for (int i = 0; i < 16; i++) acc[i] += *reinterpret_cast<const f32x4*>(rp + i * 4);
    }
    __syncthreads();
    if (w == 2 || w == 3) {
        float* rp = red + (w - 2) * 4352 + lane * 68;
#pragma unroll
        for (int i = 0; i < 16; i++) *reinterpret_cast<f32x4*>(rp + i * 4) = acc[i];
    }
    __syncthreads();
    if (w < 2) {
        float* rp = red + w * 4352 + lane * 68;
#pragma unroll
        for (int i = 0; i < 16; i++) acc[i] += *reinterpret_cast<const f32x4*>(rp + i * 4);
    }
    __syncthreads();
    if (w == 1) {
        float* rp = red + lane * 68;
#pragma unroll
        for (int i = 0; i < 16; i++) *reinterpret_cast<f32x4*>(rp + i * 4) = acc[i];
    }
    __syncthreads();
    if (w == 0) {
        float* rp = red + lane * 68;
#pragma unroll
        for (int i = 0; i < 16; i++) acc[i] += *reinterpret_cast<const f32x4*>(rp + i * 4);
#pragma unroll
        for (int qs = 0; qs < 4; qs++)
#pragma unroll
            for (int r = 0; r < 4; r++) {
                int q = qs * 16 + qd * 4 + r;
                float l = 0.f;
#pragma unroll
                for (int ww = 0; ww < 8; ww++) l += l_all[ww][q];
                float inv = 1.0f / l;
                size_t row = (size_t)(b << 12) + qbase + q;
#pragma unroll
                for (int nt = 0; nt < 4; nt++)
                    out[row * 64 + nt * 16 + c] = acc[qs * 4 + nt][r] * inv;
            }
    }
}

// ---------- launch ----------
extern "C" void kernel_launch(void* const* d_in, const int* in_sizes, int n_in,
                              void* d_out, int out_size, void* d_ws, size_t ws_size,
                              hipStream_t stream) {
    const float* emb = (const float*)d_in[0];
    const float* Wq  = (const float*)d_in[1];
    const float* bq  = (const float*)d_in[2];
    const float* Wk  = (const float*)d_in[3];
    const float* bk  = (const float*)d_in[4];
    const float* Wv  = (const float*)d_in[5];
    const float* bv  = (const float*)d_in[6];
    float* out = (float*)d_out;

    unsigned short* ws = (unsigned short*)d_ws;
    unsigned short* WtS = ws;                      // 192*1024
    unsigned short* Qb = ws + 192 * 1024;          // QTOT*64
    unsigned short* Kb = Qb + QTOT * 64;
    unsigned short* VT = Kb + QTOT * 64;
    char* region = (char*)(VT + QTOT * 64);        // byte offset 6,684,672
    size_t avail = (ws_size > 6684672) ? ws_size - 6684672 : 0;

    // proj tier: fp32 split2 (25.2 MB) > bf16 split2 (12.6 MB) > direct
    int projMode = (avail >= (size_t)2 * (NQK + NV) * 4) ? 2
                 : (avail >= (size_t)2 * (NQK + NV) * 2) ? 1 : 0;

    prep_weights<<<768, 256, 0, stream>>>(Wq, Wk, Wv, WtS);

    if (projMode == 2) {
        float* PQKp = (float*)region;
        float* PVp  = PQKp + (size_t)2 * NQK;
        proj_split<float><<<512, 256, 0, stream>>>(emb, WtS, PQKp, PVp);
        merge_proj<float><<<3072, 256, 0, stream>>>(PQKp, PVp, bq, bk, bv, Qb, Kb, VT);
    } else if (projMode == 1) {
        unsigned short* PQKp = (unsigned short*)region;
        unsigned short* PVp  = PQKp + (size_t)2 * NQK;
        proj_split<unsigned short><<<512, 256, 0, stream>>>(emb, WtS, PQKp, PVp);
        merge_proj<unsigned short><<<3072, 256, 0, stream>>>(PQKp, PVp, bq, bk, bv, Qb, Kb, VT);
    } else {
        proj_direct<<<256, 256, 0, stream>>>(emb, WtS, bq, bk, bv, Qb, Kb, VT);
    }

    attn<<<256, 512, 0, stream>>>(Qb, Kb, VT, out);
}